// Round 1
// baseline (766.973 us; speedup 1.0000x reference)
//
#include <hip/hip_runtime.h>

namespace {

constexpr int kT1   = 234;
constexpr int kT    = 469;          // sequence length
constexpr int kB    = 64;
constexpr int kC    = 1024;
constexpr int kH    = 16;
constexpr int kHD   = 64;
constexpr int kM    = kB * kT;      // 30016 rows
constexpr int kVPad = 480;          // padded T for v^T layout (15 tiles of 32)
constexpr float kScale = 0.125f;    // 1/sqrt(64)

typedef _Float16 f16;
typedef _Float16 f16x8 __attribute__((ext_vector_type(8)));
typedef float    f32x4 __attribute__((ext_vector_type(4)));

__device__ __forceinline__ void gload16(const void* g, void* l) {
  __builtin_amdgcn_global_load_lds(
      (const __attribute__((address_space(1))) unsigned int*)g,
      (__attribute__((address_space(3))) unsigned int*)l, 16, 0, 0);
}

// ---------------- cast fp32 -> fp16 (vectorized) ----------------
__global__ __launch_bounds__(256) void cast_kernel(const float* __restrict__ in,
                                                   f16* __restrict__ out, int n4) {
  int i = blockIdx.x * blockDim.x + threadIdx.x;
  int stride = gridDim.x * blockDim.x;
  for (int j = i; j < n4; j += stride) {
    float4 v = reinterpret_cast<const float4*>(in)[j];
    union { f16 h[4]; unsigned long long u; } pk;
    pk.h[0] = (f16)v.x; pk.h[1] = (f16)v.y; pk.h[2] = (f16)v.z; pk.h[3] = (f16)v.w;
    reinterpret_cast<unsigned long long*>(out)[j] = pk.u;
  }
}

// ---------------- transpose + cast: W[K0][N0] -> Wt[N0][K0] fp16 ----------------
__global__ __launch_bounds__(256) void transpose_cast(const float* __restrict__ W,
                                                      f16* __restrict__ Wt,
                                                      int K0, int N0) {
  __shared__ float tile[32][33];
  int kb = blockIdx.x * 32, nb = blockIdx.y * 32;
  int tx = threadIdx.x & 31, ty = threadIdx.x >> 5;
  #pragma unroll
  for (int r = ty; r < 32; r += 8) tile[r][tx] = W[(size_t)(kb + r) * N0 + nb + tx];
  __syncthreads();
  #pragma unroll
  for (int r = ty; r < 32; r += 8) Wt[(size_t)(nb + r) * K0 + kb + tx] = (f16)tile[tx][r];
}

// ---------------- GEMM: A[M][1024] * Bt[N][1024]^T (+bias) ----------------
// EPI==0: QKV epilogue -> scatter q,k as [B,H,T,64] fp16, v as [B,H,64,480] fp16 (transposed)
// EPI==1: proj epilogue -> fp32 out[M][1024]
template <int EPI>
__global__ __launch_bounds__(256) void gemm_f16(
    const f16* __restrict__ A, const f16* __restrict__ Bt,
    const float* __restrict__ bias,
    f16* __restrict__ qh, f16* __restrict__ kh, f16* __restrict__ vt,
    float* __restrict__ outp) {
  __shared__ __align__(16) f16 As[128 * 32];
  __shared__ __align__(16) f16 Bs[128 * 32];
  const int K = 1024;
  int m0 = blockIdx.y * 128;
  int n0 = blockIdx.x * 128;
  int tid = threadIdx.x;
  int w = tid >> 6, lane = tid & 63;
  int wr = w >> 1, wc = w & 1;
  int lhi = lane >> 4, llo = lane & 15;

  const f32x4 zero4 = {0.f, 0.f, 0.f, 0.f};
  f32x4 acc[4][4];
  #pragma unroll
  for (int a = 0; a < 4; a++)
    #pragma unroll
    for (int b = 0; b < 4; b++) acc[a][b] = zero4;

  for (int k0 = 0; k0 < K; k0 += 32) {
    __syncthreads();
    #pragma unroll
    for (int i = 0; i < 2; i++) {
      int c = w * 128 + i * 64 + lane;       // 16B-chunk index in tile
      int row = c >> 2, kc = c & 3;          // 4 chunks per 32-half row
      int gm = m0 + row; if (gm > kM - 1) gm = kM - 1;
      gload16(A  + (size_t)gm * K + k0 + kc * 8,
              As + (size_t)(w * 128 + i * 64) * 8);
      gload16(Bt + (size_t)(n0 + row) * K + k0 + kc * 8,
              Bs + (size_t)(w * 128 + i * 64) * 8);
    }
    __syncthreads();
    f16x8 av[4], bv[4];
    #pragma unroll
    for (int a = 0; a < 4; a++)
      av[a] = *reinterpret_cast<const f16x8*>(&As[(wr * 64 + a * 16 + llo) * 32 + lhi * 8]);
    #pragma unroll
    for (int b = 0; b < 4; b++)
      bv[b] = *reinterpret_cast<const f16x8*>(&Bs[(wc * 64 + b * 16 + llo) * 32 + lhi * 8]);
    #pragma unroll
    for (int a = 0; a < 4; a++)
      #pragma unroll
      for (int b = 0; b < 4; b++)
        acc[a][b] = __builtin_amdgcn_mfma_f32_16x16x32_f16(av[a], bv[b], acc[a][b], 0, 0, 0);
  }

  float bs[4];
  #pragma unroll
  for (int b = 0; b < 4; b++) bs[b] = bias[n0 + wc * 64 + b * 16 + llo];

  #pragma unroll
  for (int a = 0; a < 4; a++) {
    #pragma unroll
    for (int r = 0; r < 4; r++) {
      int row = m0 + wr * 64 + a * 16 + lhi * 4 + r;
      if (row < kM) {
        int bb = row / kT;
        int t  = row - bb * kT;
        #pragma unroll
        for (int b = 0; b < 4; b++) {
          int n = n0 + wc * 64 + b * 16 + llo;
          float v = acc[a][b][r] + bs[b];
          if constexpr (EPI == 0) {
            int which = n >> 10;        // 0:q 1:k 2:v  (uniform per block)
            int nn = n & 1023;
            int h = nn >> 6, d = nn & 63;
            int bh = bb * kH + h;
            f16 hv = (f16)v;
            if (which == 0)      qh[((size_t)bh * kT + t) * kHD + d] = hv;
            else if (which == 1) kh[((size_t)bh * kT + t) * kHD + d] = hv;
            else                 vt[((size_t)bh * kHD + d) * kVPad + t] = hv;
          } else {
            outp[(size_t)row * kC + n] = v;
          }
        }
      }
    }
  }
}

// ---------------- flash attention ----------------
// grid: (B*H*4) blocks; block = 4 waves, wave owns 32 q-rows of a 128-row q-tile.
__global__ __launch_bounds__(256) void attn_kernel(
    const f16* __restrict__ qh, const f16* __restrict__ kh,
    const f16* __restrict__ vt, f16* __restrict__ y) {
  __shared__ __align__(16) f16 P_lds[4][32 * 32];
  int tid = threadIdx.x;
  int w = tid >> 6, lane = tid & 63;
  int lhi = lane >> 4, llo = lane & 15;
  int bid = blockIdx.x;
  int bh = bid >> 2, qt = bid & 3;
  int bb = bh >> 4, h = bh & 15;
  const f16* qb = qh + (size_t)bh * kT * kHD;
  const f16* kb = kh + (size_t)bh * kT * kHD;
  const f16* vb = vt + (size_t)bh * kHD * kVPad;
  int qbase = qt * 128 + w * 32;

  // Q fragments in registers: 2 row-frags x 2 k-steps
  f16x8 qf[2][2];
  #pragma unroll
  for (int rf = 0; rf < 2; rf++) {
    int qr = qbase + rf * 16 + llo;
    if (qr > kT - 1) qr = kT - 1;
    #pragma unroll
    for (int ks = 0; ks < 2; ks++)
      qf[rf][ks] = *reinterpret_cast<const f16x8*>(&qb[(size_t)qr * kHD + ks * 32 + lhi * 8]);
  }

  const f32x4 zero4 = {0.f, 0.f, 0.f, 0.f};
  f32x4 O[2][4];
  float m_[2][4], l_[2][4];
  #pragma unroll
  for (int rf = 0; rf < 2; rf++) {
    #pragma unroll
    for (int d = 0; d < 4; d++) O[rf][d] = zero4;
    #pragma unroll
    for (int r = 0; r < 4; r++) { m_[rf][r] = -1e30f; l_[rf][r] = 0.f; }
  }

  for (int kt = 0; kt < 15; kt++) {
    int kbase = kt * 32;
    // ---- S = Q K^T ----
    f32x4 s[2][2];
    #pragma unroll
    for (int rf = 0; rf < 2; rf++)
      #pragma unroll
      for (int kf = 0; kf < 2; kf++) s[rf][kf] = zero4;
    #pragma unroll
    for (int kf = 0; kf < 2; kf++) {
      int ky = kbase + kf * 16 + llo;
      if (ky > kT - 1) ky = kT - 1;
      #pragma unroll
      for (int ks = 0; ks < 2; ks++) {
        f16x8 kv = *reinterpret_cast<const f16x8*>(&kb[(size_t)ky * kHD + ks * 32 + lhi * 8]);
        #pragma unroll
        for (int rf = 0; rf < 2; rf++)
          s[rf][kf] = __builtin_amdgcn_mfma_f32_16x16x32_f16(qf[rf][ks], kv, s[rf][kf], 0, 0, 0);
      }
    }
    // ---- scale + additive mask ----
    float p[2][2][4];
    #pragma unroll
    for (int rf = 0; rf < 2; rf++)
      #pragma unroll
      for (int kf = 0; kf < 2; kf++) {
        int ki = kbase + kf * 16 + llo;
        #pragma unroll
        for (int r = 0; r < 4; r++) {
          int qi = qbase + rf * 16 + lhi * 4 + r;
          float val = s[rf][kf][r] * kScale;
          bool cross = (qi == 0) || (ki == 0) || ((qi <= kT1) != (ki <= kT1));
          val += cross ? 1.0f : 0.0f;
          if (ki >= kT) val = -30000.f;   // padded keys
          p[rf][kf][r] = val;
        }
      }
    // ---- online softmax update ----
    #pragma unroll
    for (int rf = 0; rf < 2; rf++) {
      float corr[4];
      #pragma unroll
      for (int r = 0; r < 4; r++) {
        float mx = fmaxf(p[rf][0][r], p[rf][1][r]);
        #pragma unroll
        for (int off = 8; off >= 1; off >>= 1)
          mx = fmaxf(mx, __shfl_xor(mx, off, 64));
        float mn = fmaxf(m_[rf][r], mx);
        corr[r] = __expf(m_[rf][r] - mn);
        m_[rf][r] = mn;
        float p0 = __expf(p[rf][0][r] - mn);
        float p1 = __expf(p[rf][1][r] - mn);
        p[rf][0][r] = p0; p[rf][1][r] = p1;
        float sm = p0 + p1;
        #pragma unroll
        for (int off = 8; off >= 1; off >>= 1)
          sm += __shfl_xor(sm, off, 64);
        l_[rf][r] = l_[rf][r] * corr[r] + sm;
      }
      #pragma unroll
      for (int d = 0; d < 4; d++)
        #pragma unroll
        for (int r = 0; r < 4; r++) O[rf][d][r] *= corr[r];
      // spill P (D-layout) to LDS so PV can read A-layout frags
      #pragma unroll
      for (int kf = 0; kf < 2; kf++)
        #pragma unroll
        for (int r = 0; r < 4; r++)
          P_lds[w][(rf * 16 + lhi * 4 + r) * 32 + kf * 16 + llo] = (f16)p[rf][kf][r];
    }
    // ---- O += P V ----
    f16x8 pa[2];
    #pragma unroll
    for (int rf = 0; rf < 2; rf++)
      pa[rf] = *reinterpret_cast<const f16x8*>(&P_lds[w][(rf * 16 + llo) * 32 + lhi * 8]);
    #pragma unroll
    for (int d = 0; d < 4; d++) {
      f16x8 vv = *reinterpret_cast<const f16x8*>(&vb[(size_t)(d * 16 + llo) * kVPad + kbase + lhi * 8]);
      #pragma unroll
      for (int rf = 0; rf < 2; rf++)
        O[rf][d] = __builtin_amdgcn_mfma_f32_16x16x32_f16(pa[rf], vv, O[rf][d], 0, 0, 0);
    }
  }
  // ---- normalize + store y[B,T,C] fp16 ----
  #pragma unroll
  for (int rf = 0; rf < 2; rf++)
    #pragma unroll
    for (int r = 0; r < 4; r++) {
      int qi = qbase + rf * 16 + lhi * 4 + r;
      if (qi < kT) {
        float inv = 1.0f / l_[rf][r];
        size_t base = ((size_t)bb * kT + qi) * kC + h * kHD;
        #pragma unroll
        for (int d = 0; d < 4; d++)
          y[base + d * 16 + llo] = (f16)(O[rf][d][r] * inv);
      }
    }
}

}  // namespace

extern "C" void kernel_launch(void* const* d_in, const int* in_sizes, int n_in,
                              void* d_out, int out_size, void* d_ws, size_t ws_size,
                              hipStream_t stream) {
  const float* x  = (const float*)d_in[0];
  const float* Wa = (const float*)d_in[1];
  const float* ba = (const float*)d_in[2];
  const float* Wp = (const float*)d_in[3];
  const float* bp = (const float*)d_in[4];
  float* out = (float*)d_out;
  char* ws = (char*)d_ws;

  const size_t sz_xh = (size_t)kM * kC * 2;                 // 61.5 MB (x_h, later y_h)
  const size_t sz_wa = (size_t)3072 * 1024 * 2;             // 6.3 MB
  const size_t sz_wp = (size_t)1024 * 1024 * 2;             // 2.1 MB
  const size_t sz_q  = (size_t)kB * kH * kT * kHD * 2;      // 61.5 MB
  // v^T buffer: B*H*64*480*2 = 62.9 MB

  f16* xh  = (f16*)(ws);
  f16* WaT = (f16*)(ws + sz_xh);
  f16* WpT = (f16*)(ws + sz_xh + sz_wa);
  f16* qh  = (f16*)(ws + sz_xh + sz_wa + sz_wp);
  f16* kh2 = (f16*)(ws + sz_xh + sz_wa + sz_wp + sz_q);
  f16* vtt = (f16*)(ws + sz_xh + sz_wa + sz_wp + 2 * sz_q);
  f16* yh  = xh;  // x_h is dead after QKV GEMM; reuse for attention output

  cast_kernel<<<2048, 256, 0, stream>>>(x, xh, kM * kC / 4);
  transpose_cast<<<dim3(32, 96), 256, 0, stream>>>(Wa, WaT, 1024, 3072);
  transpose_cast<<<dim3(32, 32), 256, 0, stream>>>(Wp, WpT, 1024, 1024);
  gemm_f16<0><<<dim3(24, 235), 256, 0, stream>>>(xh, WaT, ba, qh, kh2, vtt, nullptr);
  attn_kernel<<<kB * kH * 4, 256, 0, stream>>>(qh, kh2, vtt, yh);
  gemm_f16<1><<<dim3(8, 235), 256, 0, stream>>>(yh, WpT, bp, nullptr, nullptr, nullptr, out);
}

// Round 2
// 698.999 us; speedup vs baseline: 1.0972x; 1.0972x over previous
//
#include <hip/hip_runtime.h>

namespace {

constexpr int kT1   = 234;
constexpr int kT    = 469;          // sequence length
constexpr int kB    = 64;
constexpr int kC    = 1024;
constexpr int kH    = 16;
constexpr int kHD   = 64;
constexpr int kM    = kB * kT;      // 30016 rows
constexpr int kVPad = 480;          // padded T for v^T layout (15 tiles of 32)
// exp2-domain constants: p = exp(s*0.125 + mask - 4) = exp2(s*c1 + mask*c2 - 4*c2)
constexpr float kC1 = 0.125f * 1.44269504089f;
constexpr float kC2 = 1.44269504089f;
constexpr float kShift = 4.0f * 1.44269504089f;

typedef _Float16 f16;
typedef _Float16 f16x8 __attribute__((ext_vector_type(8)));
typedef float    f32x4 __attribute__((ext_vector_type(4)));

__device__ __forceinline__ void gload16(const void* g, void* l) {
  __builtin_amdgcn_global_load_lds(
      (const __attribute__((address_space(1))) unsigned int*)g,
      (__attribute__((address_space(3))) unsigned int*)l, 16, 0, 0);
}

// ---------------- cast fp32 -> fp16 (vectorized) ----------------
__global__ __launch_bounds__(256) void cast_kernel(const float* __restrict__ in,
                                                   f16* __restrict__ out, int n4) {
  int i = blockIdx.x * blockDim.x + threadIdx.x;
  int stride = gridDim.x * blockDim.x;
  for (int j = i; j < n4; j += stride) {
    float4 v = reinterpret_cast<const float4*>(in)[j];
    union { f16 h[4]; unsigned long long u; } pk;
    pk.h[0] = (f16)v.x; pk.h[1] = (f16)v.y; pk.h[2] = (f16)v.z; pk.h[3] = (f16)v.w;
    reinterpret_cast<unsigned long long*>(out)[j] = pk.u;
  }
}

// ---------------- transpose + cast: W[K0][N0] -> Wt[N0][K0] fp16 ----------------
__global__ __launch_bounds__(256) void transpose_cast(const float* __restrict__ W,
                                                      f16* __restrict__ Wt,
                                                      int K0, int N0) {
  __shared__ float tile[32][33];
  int kb = blockIdx.x * 32, nb = blockIdx.y * 32;
  int tx = threadIdx.x & 31, ty = threadIdx.x >> 5;
  #pragma unroll
  for (int r = ty; r < 32; r += 8) tile[r][tx] = W[(size_t)(kb + r) * N0 + nb + tx];
  __syncthreads();
  #pragma unroll
  for (int r = ty; r < 32; r += 8) Wt[(size_t)(nb + r) * K0 + kb + tx] = (f16)tile[tx][r];
}

// ---------------- v transpose: [bh][469][64] -> [bh][64][480] with per-32-tile
// key permutation pi(c) = (c&15)*2 + (c>>4)  (storage pos q holds key (q>>1)+(q&1)*16)
__global__ __launch_bounds__(256) void vtrans(const f16* __restrict__ in,
                                              f16* __restrict__ out) {
  __shared__ f16 tile[64][66];
  int bid = blockIdx.x;
  int bh = bid >> 3, tt = bid & 7;
  int t0 = tt * 64;
  int tx = threadIdx.x & 63, ty = threadIdx.x >> 6;
  const f16* src = in + (size_t)bh * kT * kHD;
  #pragma unroll
  for (int rr = ty; rr < 64; rr += 4) {
    int t = t0 + rr;
    tile[rr][tx] = (t < kT) ? src[(size_t)t * kHD + tx] : (f16)0.f;
  }
  __syncthreads();
  f16* dst = out + (size_t)bh * kHD * kVPad;
  int q = tx & 31, sub = tx >> 5;
  int tloc = sub * 32 + (q >> 1) + (q & 1) * 16;   // original local t for storage pos tx
  int tout = t0 + tx;
  if (tout < kVPad) {
    #pragma unroll
    for (int dd = ty; dd < 64; dd += 4)
      dst[(size_t)dd * kVPad + tout] = tile[tloc][dd];
  }
}

// ---------------- GEMM: A[M][1024] * Bt[N][1024]^T (+bias), dbuf 2-phase + T2 swizzle
// EPI==0: QKV epilogue -> q,k,v all as [B,H,T,64] fp16 (v into scratch, transposed later)
// EPI==1: proj epilogue -> fp32 out[M][1024]
template <int EPI>
__global__ __launch_bounds__(256) void gemm_f16(
    const f16* __restrict__ A, const f16* __restrict__ Bt,
    const float* __restrict__ bias,
    f16* __restrict__ qh, f16* __restrict__ kh, f16* __restrict__ vh,
    float* __restrict__ outp) {
  __shared__ __align__(16) f16 As[2][128 * 32];
  __shared__ __align__(16) f16 Bs[2][128 * 32];
  const int K = 1024;
  int m0 = blockIdx.y * 128;
  int n0 = blockIdx.x * 128;
  int tid = threadIdx.x;
  int w = tid >> 6, lane = tid & 63;
  int wr = w >> 1, wc = w & 1;
  int lhi = lane >> 4, llo = lane & 15;

  const f32x4 zero4 = {0.f, 0.f, 0.f, 0.f};
  f32x4 acc[4][4];
  #pragma unroll
  for (int a = 0; a < 4; a++)
    #pragma unroll
    for (int b = 0; b < 4; b++) acc[a][b] = zero4;

  // stage k-tile k0 into buffer buf; LDS linear, global source pre-swizzled:
  // LDS chunk (row, slot) holds global k-chunk kc = slot ^ ((row>>1)&3)
  auto stage = [&](int k0, int buf) {
    #pragma unroll
    for (int i = 0; i < 2; i++) {
      int c = w * 128 + i * 64 + lane;       // 16B-chunk index in tile (linear LDS)
      int row = c >> 2, slot = c & 3;
      int kc = slot ^ ((row >> 1) & 3);
      int gm = m0 + row; if (gm > kM - 1) gm = kM - 1;
      gload16(A  + (size_t)gm * K + k0 + kc * 8, &As[buf][(size_t)c * 8]);
      gload16(Bt + (size_t)(n0 + row) * K + k0 + kc * 8, &Bs[buf][(size_t)c * 8]);
    }
  };

  stage(0, 0);
  __syncthreads();
  for (int t = 0; t < 32; ++t) {
    int cur = t & 1;
    if (t < 31) stage((t + 1) * 32, cur ^ 1);   // issue next tile BEFORE compute
    f16x8 av[4], bv[4];
    #pragma unroll
    for (int a = 0; a < 4; a++) {
      int row = wr * 64 + a * 16 + llo;
      av[a] = *reinterpret_cast<const f16x8*>(
          &As[cur][row * 32 + ((lhi ^ ((row >> 1) & 3)) << 3)]);
    }
    #pragma unroll
    for (int b = 0; b < 4; b++) {
      int row = wc * 64 + b * 16 + llo;
      bv[b] = *reinterpret_cast<const f16x8*>(
          &Bs[cur][row * 32 + ((lhi ^ ((row >> 1) & 3)) << 3)]);
    }
    #pragma unroll
    for (int a = 0; a < 4; a++)
      #pragma unroll
      for (int b = 0; b < 4; b++)
        acc[a][b] = __builtin_amdgcn_mfma_f32_16x16x32_f16(av[a], bv[b], acc[a][b], 0, 0, 0);
    __syncthreads();   // one barrier per K-step (drains stage loads + ds reads)
  }

  float bs[4];
  #pragma unroll
  for (int b = 0; b < 4; b++) bs[b] = bias[n0 + wc * 64 + b * 16 + llo];

  if constexpr (EPI == 0) {
    const int which = n0 >> 10;            // 0:q 1:k 2:v (uniform per block)
    f16* dst = (which == 0) ? qh : (which == 1) ? kh : vh;
    #pragma unroll
    for (int a = 0; a < 4; a++) {
      #pragma unroll
      for (int r = 0; r < 4; r++) {
        int row = m0 + wr * 64 + a * 16 + lhi * 4 + r;
        if (row < kM) {
          int bb = row / kT;
          int t  = row - bb * kT;
          size_t rb = ((size_t)(bb * kH) * kT + t) * kHD;
          #pragma unroll
          for (int b = 0; b < 4; b++) {
            int n = n0 + wc * 64 + b * 16 + llo;
            int h = (n >> 6) & 15, d = n & 63;
            dst[rb + (size_t)h * kT * kHD + d] = (f16)(acc[a][b][r] + bs[b]);
          }
        }
      }
    }
  } else {
    #pragma unroll
    for (int a = 0; a < 4; a++) {
      #pragma unroll
      for (int r = 0; r < 4; r++) {
        int row = m0 + wr * 64 + a * 16 + lhi * 4 + r;
        if (row < kM) {
          #pragma unroll
          for (int b = 0; b < 4; b++) {
            int n = n0 + wc * 64 + b * 16 + llo;
            outp[(size_t)row * kC + n] = acc[a][b][r] + bs[b];
          }
        }
      }
    }
  }
}

// ---------------- attention: fixed-shift softmax (no online max) ----------------
// grid: (B*H*4) blocks; block = 4 waves, wave owns 32 q-rows of a 128-row q-tile.
__global__ __launch_bounds__(256) void attn_kernel(
    const f16* __restrict__ qh, const f16* __restrict__ kh,
    const f16* __restrict__ vt, f16* __restrict__ y) {
  __shared__ __align__(16) f16 P_lds[4][32 * 32];   // per-wave 32x32, 64B rows
  int tid = threadIdx.x;
  int w = tid >> 6, lane = tid & 63;
  int lhi = lane >> 4, llo = lane & 15;
  int bid = blockIdx.x;
  int bh = bid >> 2, qt = bid & 3;
  int bb = bh >> 4, h = bh & 15;
  const f16* qb = qh + (size_t)bh * kT * kHD;
  const f16* kb = kh + (size_t)bh * kT * kHD;
  const f16* vb = vt + (size_t)bh * kHD * kVPad;
  int qbase = qt * 128 + w * 32;

  // Q fragments in registers: 2 row-frags x 2 k-steps
  f16x8 qf[2][2];
  bool qz[2][4], qle[2][4];
  #pragma unroll
  for (int rf = 0; rf < 2; rf++) {
    int qr = qbase + rf * 16 + llo;
    if (qr > kT - 1) qr = kT - 1;
    #pragma unroll
    for (int ks = 0; ks < 2; ks++)
      qf[rf][ks] = *reinterpret_cast<const f16x8*>(&qb[(size_t)qr * kHD + ks * 32 + lhi * 8]);
    #pragma unroll
    for (int r = 0; r < 4; r++) {
      int qi = qbase + rf * 16 + lhi * 4 + r;
      qz[rf][r]  = (qi == 0);
      qle[rf][r] = (qi <= kT1);
    }
  }

  const f32x4 zero4 = {0.f, 0.f, 0.f, 0.f};
  f32x4 O[2][4];
  float lp[2][4];
  #pragma unroll
  for (int rf = 0; rf < 2; rf++) {
    #pragma unroll
    for (int d = 0; d < 4; d++) O[rf][d] = zero4;
    #pragma unroll
    for (int r = 0; r < 4; r++) lp[rf][r] = 0.f;
  }

  for (int kt = 0; kt < 15; kt++) {
    int kbase = kt * 32;
    // ---- S = Q K^T ----
    f32x4 s[2][2];
    #pragma unroll
    for (int rf = 0; rf < 2; rf++)
      #pragma unroll
      for (int kf = 0; kf < 2; kf++) s[rf][kf] = zero4;
    __builtin_amdgcn_s_setprio(1);
    #pragma unroll
    for (int kf = 0; kf < 2; kf++) {
      int ky = kbase + kf * 16 + llo;
      if (ky > kT - 1) ky = kT - 1;
      #pragma unroll
      for (int ks = 0; ks < 2; ks++) {
        f16x8 kv = *reinterpret_cast<const f16x8*>(&kb[(size_t)ky * kHD + ks * 32 + lhi * 8]);
        #pragma unroll
        for (int rf = 0; rf < 2; rf++)
          s[rf][kf] = __builtin_amdgcn_mfma_f32_16x16x32_f16(qf[rf][ks], kv, s[rf][kf], 0, 0, 0);
      }
    }
    __builtin_amdgcn_s_setprio(0);
    // ---- P = exp2(s*c1 + mask*c2 - shift); accumulate per-lane row-sums ----
    int ki0 = kbase + llo;
    int ki1 = kbase + 16 + llo;
    bool kz0 = (ki0 == 0), kle0 = (ki0 <= kT1);
    bool kz1 = (ki1 == 0), kle1 = (ki1 <= kT1);
    bool k1ok = (ki1 < kT);                 // ki0 < 469 always (max 463)
    #pragma unroll
    for (int rf = 0; rf < 2; rf++) {
      #pragma unroll
      for (int r = 0; r < 4; r++) {
        bool c0 = qz[rf][r] | kz0 | (qle[rf][r] != kle0);
        bool c1 = qz[rf][r] | kz1 | (qle[rf][r] != kle1);
        float v0 = s[rf][0][r] * kC1 + (c0 ? (kC2 - kShift) : -kShift);
        float v1 = s[rf][1][r] * kC1 + (c1 ? (kC2 - kShift) : -kShift);
        float p0 = __builtin_exp2f(v0);
        float p1 = k1ok ? __builtin_exp2f(v1) : 0.f;
        lp[rf][r] += p0 + p1;
        // packed u32 store: f16 pos = llo*2+kf (key-permuted layout), chunk-swizzled
        union { f16 hh[2]; unsigned u; } pk;
        pk.hh[0] = (f16)p0; pk.hh[1] = (f16)p1;
        int row = rf * 16 + lhi * 4 + r;
        int dw = row * 16 + (((llo >> 2) ^ ((row >> 1) & 3)) << 2) + (llo & 3);
        reinterpret_cast<unsigned*>(P_lds[w])[dw] = pk.u;
      }
    }
    // ---- O += P V  (V stored with matching key permutation) ----
    f16x8 pa[2];
    #pragma unroll
    for (int rf = 0; rf < 2; rf++) {
      int row = rf * 16 + llo;
      pa[rf] = *reinterpret_cast<const f16x8*>(
          &P_lds[w][row * 32 + ((lhi ^ ((row >> 1) & 3)) << 3)]);
    }
    __builtin_amdgcn_s_setprio(1);
    #pragma unroll
    for (int d = 0; d < 4; d++) {
      f16x8 vv = *reinterpret_cast<const f16x8*>(
          &vb[(size_t)(d * 16 + llo) * kVPad + kbase + lhi * 8]);
      #pragma unroll
      for (int rf = 0; rf < 2; rf++)
        O[rf][d] = __builtin_amdgcn_mfma_f32_16x16x32_f16(pa[rf], vv, O[rf][d], 0, 0, 0);
    }
    __builtin_amdgcn_s_setprio(0);
  }
  // ---- row-sum reduce (once), normalize + store y[B,T,C] fp16 ----
  #pragma unroll
  for (int rf = 0; rf < 2; rf++)
    #pragma unroll
    for (int r = 0; r < 4; r++) {
      float l = lp[rf][r];
      l += __shfl_xor(l, 1, 64);
      l += __shfl_xor(l, 2, 64);
      l += __shfl_xor(l, 4, 64);
      l += __shfl_xor(l, 8, 64);
      int qi = qbase + rf * 16 + lhi * 4 + r;
      if (qi < kT) {
        float inv = 1.0f / l;
        size_t base = ((size_t)bb * kT + qi) * kC + h * kHD;
        #pragma unroll
        for (int d = 0; d < 4; d++)
          y[base + d * 16 + llo] = (f16)(O[rf][d][r] * inv);
      }
    }
}

}  // namespace

extern "C" void kernel_launch(void* const* d_in, const int* in_sizes, int n_in,
                              void* d_out, int out_size, void* d_ws, size_t ws_size,
                              hipStream_t stream) {
  const float* x  = (const float*)d_in[0];
  const float* Wa = (const float*)d_in[1];
  const float* ba = (const float*)d_in[2];
  const float* Wp = (const float*)d_in[3];
  const float* bp = (const float*)d_in[4];
  float* out = (float*)d_out;
  char* ws = (char*)d_ws;

  const size_t sz_xh = (size_t)kM * kC * 2;                 // 61.5 MB (x_h, later y_h)
  const size_t sz_wa = (size_t)3072 * 1024 * 2;             // 6.3 MB
  const size_t sz_wp = (size_t)1024 * 1024 * 2;             // 2.1 MB
  const size_t sz_q  = (size_t)kB * kH * kT * kHD * 2;      // 61.5 MB

  f16* xh  = (f16*)(ws);
  f16* WaT = (f16*)(ws + sz_xh);
  f16* WpT = (f16*)(ws + sz_xh + sz_wa);
  f16* qh  = (f16*)(ws + sz_xh + sz_wa + sz_wp);
  f16* kh2 = (f16*)(ws + sz_xh + sz_wa + sz_wp + sz_q);
  f16* vtt = (f16*)(ws + sz_xh + sz_wa + sz_wp + 2 * sz_q); // [bh][64][480], 62.9 MB
  f16* yh  = xh;                 // x_h dead after QKV GEMM
  f16* vtmp = (f16*)d_out;       // d_out (123 MB fp32) as scratch for v in [bh][t][d];
                                 // overwritten entirely by the proj GEMM at the end

  cast_kernel<<<2048, 256, 0, stream>>>(x, xh, kM * kC / 4);
  transpose_cast<<<dim3(32, 96), 256, 0, stream>>>(Wa, WaT, 1024, 3072);
  transpose_cast<<<dim3(32, 32), 256, 0, stream>>>(Wp, WpT, 1024, 1024);
  gemm_f16<0><<<dim3(24, 235), 256, 0, stream>>>(xh, WaT, ba, qh, kh2, vtmp, nullptr);
  vtrans<<<kB * kH * 8, 256, 0, stream>>>(vtmp, vtt);
  attn_kernel<<<kB * kH * 4, 256, 0, stream>>>(qh, kh2, vtt, yh);
  gemm_f16<1><<<dim3(8, 235), 256, 0, stream>>>(yh, WpT, bp, nullptr, nullptr, nullptr, out);
}

// Round 3
// 656.544 us; speedup vs baseline: 1.1682x; 1.0647x over previous
//
#include <hip/hip_runtime.h>

namespace {

constexpr int kT1   = 234;
constexpr int kT    = 469;          // sequence length
constexpr int kB    = 64;
constexpr int kC    = 1024;
constexpr int kH    = 16;
constexpr int kHD   = 64;
constexpr int kM    = kB * kT;      // 30016 rows
constexpr int kVPad = 480;          // padded T for v^T layout (15 tiles of 32)
// exp2-domain constants: p = exp(s*0.125 + mask - 4) = exp2(s*c1 + mask*c2 - 4*c2)
constexpr float kC1 = 0.125f * 1.44269504089f;
constexpr float kC2 = 1.44269504089f;
constexpr float kShift = 4.0f * 1.44269504089f;

typedef _Float16 f16;
typedef _Float16 f16x8 __attribute__((ext_vector_type(8)));
typedef float    f32x4 __attribute__((ext_vector_type(4)));

__device__ __forceinline__ void gload16(const void* g, void* l) {
  __builtin_amdgcn_global_load_lds(
      (const __attribute__((address_space(1))) unsigned int*)g,
      (__attribute__((address_space(3))) unsigned int*)l, 16, 0, 0);
}

// ---------------- cast fp32 -> fp16 (vectorized) ----------------
__global__ __launch_bounds__(256) void cast_kernel(const float* __restrict__ in,
                                                   f16* __restrict__ out, int n4) {
  int i = blockIdx.x * blockDim.x + threadIdx.x;
  int stride = gridDim.x * blockDim.x;
  for (int j = i; j < n4; j += stride) {
    float4 v = reinterpret_cast<const float4*>(in)[j];
    union { f16 h[4]; unsigned long long u; } pk;
    pk.h[0] = (f16)v.x; pk.h[1] = (f16)v.y; pk.h[2] = (f16)v.z; pk.h[3] = (f16)v.w;
    reinterpret_cast<unsigned long long*>(out)[j] = pk.u;
  }
}

// ---------------- transpose + cast: W[K0][N0] -> Wt[N0][K0] fp16 ----------------
__global__ __launch_bounds__(256) void transpose_cast(const float* __restrict__ W,
                                                      f16* __restrict__ Wt,
                                                      int K0, int N0) {
  __shared__ float tile[32][33];
  int kb = blockIdx.x * 32, nb = blockIdx.y * 32;
  int tx = threadIdx.x & 31, ty = threadIdx.x >> 5;
  #pragma unroll
  for (int r = ty; r < 32; r += 8) tile[r][tx] = W[(size_t)(kb + r) * N0 + nb + tx];
  __syncthreads();
  #pragma unroll
  for (int r = ty; r < 32; r += 8) Wt[(size_t)(nb + r) * K0 + kb + tx] = (f16)tile[tx][r];
}

// ---------------- v transpose: [bh][469][64] -> [bh][64][480] with per-32-tile
// key permutation pi(c) = (c&15)*2 + (c>>4)  (storage pos q holds key (q>>1)+(q&1)*16)
__global__ __launch_bounds__(256) void vtrans(const f16* __restrict__ in,
                                              f16* __restrict__ out) {
  __shared__ f16 tile[64][66];
  int bid = blockIdx.x;
  int bh = bid >> 3, tt = bid & 7;
  int t0 = tt * 64;
  int tx = threadIdx.x & 63, ty = threadIdx.x >> 6;
  const f16* src = in + (size_t)bh * kT * kHD;
  #pragma unroll
  for (int rr = ty; rr < 64; rr += 4) {
    int t = t0 + rr;
    tile[rr][tx] = (t < kT) ? src[(size_t)t * kHD + tx] : (f16)0.f;
  }
  __syncthreads();
  f16* dst = out + (size_t)bh * kHD * kVPad;
  int q = tx & 31, sub = tx >> 5;
  int tloc = sub * 32 + (q >> 1) + (q & 1) * 16;   // original local t for storage pos tx
  int tout = t0 + tx;
  if (tout < kVPad) {
    #pragma unroll
    for (int dd = ty; dd < 64; dd += 4)
      dst[(size_t)dd * kVPad + tout] = tile[tloc][dd];
  }
}

// ---------------- GEMM: A[M][1024] * Bt[N][1024]^T (+bias)
// 3-buffer depth-2 pipeline, counted vmcnt (never 0 in main loop), raw barriers.
// EPI==0: QKV epilogue -> q,k,v as [B,H,T,64] fp16 (v into scratch)
// EPI==1: proj epilogue -> fp32 out[M][1024]
template <int EPI>
__global__ __launch_bounds__(256, 3) void gemm_f16(
    const f16* __restrict__ A, const f16* __restrict__ Bt,
    const float* __restrict__ bias,
    f16* __restrict__ qh, f16* __restrict__ kh, f16* __restrict__ vh,
    float* __restrict__ outp, int nbx, int nblocks) {
  __shared__ __align__(16) f16 As[3][128 * 32];
  __shared__ __align__(16) f16 Bs[3][128 * 32];
  const int K = 1024;
  // bijective XCD swizzle (nblocks % 8 == 0): each XCD gets a contiguous chunk,
  // within which n varies fastest -> A-panel reuse stays in one L2.
  int flat = blockIdx.x;
  int swz = (flat & 7) * (nblocks >> 3) + (flat >> 3);
  int m0 = (swz / nbx) * 128;
  int n0 = (swz - (swz / nbx) * nbx) * 128;
  int tid = threadIdx.x;
  int w = tid >> 6, lane = tid & 63;
  int wr = w >> 1, wc = w & 1;
  int lhi = lane >> 4, llo = lane & 15;

  // staging geometry: thread handles 16B-chunks c0, c1 of each 128x32 tile.
  // LDS chunk (row, slot) holds global k-chunk kc = slot ^ ((row>>1)&3).
  int c0 = w * 128 + lane;
  int c1 = c0 + 64;
  int r0 = c0 >> 2, s0 = c0 & 3, kc0 = s0 ^ ((r0 >> 1) & 3);
  int r1 = c1 >> 2, s1 = c1 & 3, kc1 = s1 ^ ((r1 >> 1) & 3);
  int gm0 = m0 + r0; if (gm0 > kM - 1) gm0 = kM - 1;
  int gm1 = m0 + r1; if (gm1 > kM - 1) gm1 = kM - 1;
  const f16* aP0 = A + (size_t)gm0 * K + kc0 * 8;
  const f16* aP1 = A + (size_t)gm1 * K + kc1 * 8;
  const f16* bP0 = Bt + (size_t)(n0 + r0) * K + kc0 * 8;
  const f16* bP1 = Bt + (size_t)(n0 + r1) * K + kc1 * 8;
  const int ldsO0 = c0 * 8, ldsO1 = c1 * 8;

  const f32x4 zero4 = {0.f, 0.f, 0.f, 0.f};
  f32x4 acc[4][4];
  #pragma unroll
  for (int a = 0; a < 4; a++)
    #pragma unroll
    for (int b = 0; b < 4; b++) acc[a][b] = zero4;

  // per-thread ds_read offsets (constant): fragment row + chunk swizzle
  int aOff[4], bOff[4];
  #pragma unroll
  for (int a = 0; a < 4; a++) {
    int row = wr * 64 + a * 16 + llo;
    aOff[a] = row * 32 + ((lhi ^ ((row >> 1) & 3)) << 3);
  }
  #pragma unroll
  for (int b = 0; b < 4; b++) {
    int row = wc * 64 + b * 16 + llo;
    bOff[b] = row * 32 + ((lhi ^ ((row >> 1) & 3)) << 3);
  }

  auto stage = [&](int sb) {
    gload16(aP0, &As[sb][ldsO0]);
    gload16(aP1, &As[sb][ldsO1]);
    gload16(bP0, &Bs[sb][ldsO0]);
    gload16(bP1, &Bs[sb][ldsO1]);
    aP0 += 32; aP1 += 32; bP0 += 32; bP1 += 32;   // advance one K-tile (64 B)
  };

  stage(0);
  stage(1);
  int sb = 2, rb = 0;
  for (int t = 0; t < 32; ++t) {
    if (t < 30) {
      stage(sb);
      sb = (sb == 2) ? 0 : sb + 1;
      asm volatile("s_waitcnt vmcnt(8)" ::: "memory");   // tile-t stage (issued t-2) done
    } else if (t == 30) {
      asm volatile("s_waitcnt vmcnt(4)" ::: "memory");
    } else {
      asm volatile("s_waitcnt vmcnt(0)" ::: "memory");
    }
    __builtin_amdgcn_s_barrier();                        // all waves' tile-t data in LDS
    asm volatile("" ::: "memory");                       // pin ds_reads after barrier
    f16x8 av[4], bv[4];
    #pragma unroll
    for (int a = 0; a < 4; a++)
      av[a] = *reinterpret_cast<const f16x8*>(&As[rb][aOff[a]]);
    #pragma unroll
    for (int b = 0; b < 4; b++)
      bv[b] = *reinterpret_cast<const f16x8*>(&Bs[rb][bOff[b]]);
    rb = (rb == 2) ? 0 : rb + 1;
    asm volatile("s_waitcnt lgkmcnt(0)" ::: "memory");   // reads retired before barrier2
    __builtin_amdgcn_sched_barrier(0);
    __builtin_amdgcn_s_barrier();                        // WAR: buf safe to overwrite
    asm volatile("" ::: "memory");                       // pin next stage after barrier2
    #pragma unroll
    for (int a = 0; a < 4; a++)
      #pragma unroll
      for (int b = 0; b < 4; b++)
        acc[a][b] = __builtin_amdgcn_mfma_f32_16x16x32_f16(av[a], bv[b], acc[a][b], 0, 0, 0);
  }

  float bs[4];
  #pragma unroll
  for (int b = 0; b < 4; b++) bs[b] = bias[n0 + wc * 64 + b * 16 + llo];

  if constexpr (EPI == 0) {
    const int which = n0 >> 10;            // 0:q 1:k 2:v (uniform per block)
    f16* dst = (which == 0) ? qh : (which == 1) ? kh : vh;
    #pragma unroll
    for (int a = 0; a < 4; a++) {
      #pragma unroll
      for (int r = 0; r < 4; r++) {
        int row = m0 + wr * 64 + a * 16 + lhi * 4 + r;
        if (row < kM) {
          int bb = row / kT;
          int t  = row - bb * kT;
          size_t rbase = ((size_t)(bb * kH) * kT + t) * kHD;
          #pragma unroll
          for (int b = 0; b < 4; b++) {
            int n = n0 + wc * 64 + b * 16 + llo;
            int h = (n >> 6) & 15, d = n & 63;
            dst[rbase + (size_t)h * kT * kHD + d] = (f16)(acc[a][b][r] + bs[b]);
          }
        }
      }
    }
  } else {
    #pragma unroll
    for (int a = 0; a < 4; a++) {
      #pragma unroll
      for (int r = 0; r < 4; r++) {
        int row = m0 + wr * 64 + a * 16 + lhi * 4 + r;
        if (row < kM) {
          #pragma unroll
          for (int b = 0; b < 4; b++) {
            int n = n0 + wc * 64 + b * 16 + llo;
            outp[(size_t)row * kC + n] = acc[a][b][r] + bs[b];
          }
        }
      }
    }
  }
}

// ---------------- attention: fixed-shift softmax (no online max) ----------------
// grid: (B*H*4) blocks; block = 4 waves, wave owns 32 q-rows of a 128-row q-tile.
__global__ __launch_bounds__(256) void attn_kernel(
    const f16* __restrict__ qh, const f16* __restrict__ kh,
    const f16* __restrict__ vt, f16* __restrict__ y) {
  __shared__ __align__(16) f16 P_lds[4][32 * 32];   // per-wave 32x32, 64B rows
  int tid = threadIdx.x;
  int w = tid >> 6, lane = tid & 63;
  int lhi = lane >> 4, llo = lane & 15;
  // XCD swizzle: 4096 blocks -> chunks of 512 per XCD; same-head q-tiles stay on one L2
  int bid = (blockIdx.x & 7) * 512 + (blockIdx.x >> 3);
  int bh = bid >> 2, qt = bid & 3;
  int bb = bh >> 4, h = bh & 15;
  const f16* qb = qh + (size_t)bh * kT * kHD;
  const f16* kb = kh + (size_t)bh * kT * kHD;
  const f16* vb = vt + (size_t)bh * kHD * kVPad;
  int qbase = qt * 128 + w * 32;

  // Q fragments in registers: 2 row-frags x 2 k-steps
  f16x8 qf[2][2];
  bool qz[2][4], qle[2][4];
  #pragma unroll
  for (int rf = 0; rf < 2; rf++) {
    int qr = qbase + rf * 16 + llo;
    if (qr > kT - 1) qr = kT - 1;
    #pragma unroll
    for (int ks = 0; ks < 2; ks++)
      qf[rf][ks] = *reinterpret_cast<const f16x8*>(&qb[(size_t)qr * kHD + ks * 32 + lhi * 8]);
    #pragma unroll
    for (int r = 0; r < 4; r++) {
      int qi = qbase + rf * 16 + lhi * 4 + r;
      qz[rf][r]  = (qi == 0);
      qle[rf][r] = (qi <= kT1);
    }
  }

  const f32x4 zero4 = {0.f, 0.f, 0.f, 0.f};
  f32x4 O[2][4];
  float lp[2][4];
  #pragma unroll
  for (int rf = 0; rf < 2; rf++) {
    #pragma unroll
    for (int d = 0; d < 4; d++) O[rf][d] = zero4;
    #pragma unroll
    for (int r = 0; r < 4; r++) lp[rf][r] = 0.f;
  }

  for (int kt = 0; kt < 15; kt++) {
    int kbase = kt * 32;
    // ---- S = Q K^T ----
    f32x4 s[2][2];
    #pragma unroll
    for (int rf = 0; rf < 2; rf++)
      #pragma unroll
      for (int kf = 0; kf < 2; kf++) s[rf][kf] = zero4;
    __builtin_amdgcn_s_setprio(1);
    #pragma unroll
    for (int kf = 0; kf < 2; kf++) {
      int ky = kbase + kf * 16 + llo;
      if (ky > kT - 1) ky = kT - 1;
      #pragma unroll
      for (int ks = 0; ks < 2; ks++) {
        f16x8 kv = *reinterpret_cast<const f16x8*>(&kb[(size_t)ky * kHD + ks * 32 + lhi * 8]);
        #pragma unroll
        for (int rf = 0; rf < 2; rf++)
          s[rf][kf] = __builtin_amdgcn_mfma_f32_16x16x32_f16(qf[rf][ks], kv, s[rf][kf], 0, 0, 0);
      }
    }
    __builtin_amdgcn_s_setprio(0);
    // ---- P = exp2(s*c1 + mask*c2 - shift); accumulate per-lane row-sums ----
    int ki0 = kbase + llo;
    int ki1 = kbase + 16 + llo;
    bool kz0 = (ki0 == 0), kle0 = (ki0 <= kT1);
    bool kz1 = (ki1 == 0), kle1 = (ki1 <= kT1);
    bool k1ok = (ki1 < kT);                 // ki0 < 469 always (max 463)
    #pragma unroll
    for (int rf = 0; rf < 2; rf++) {
      #pragma unroll
      for (int r = 0; r < 4; r++) {
        bool c0 = qz[rf][r] | kz0 | (qle[rf][r] != kle0);
        bool c1 = qz[rf][r] | kz1 | (qle[rf][r] != kle1);
        float v0 = s[rf][0][r] * kC1 + (c0 ? (kC2 - kShift) : -kShift);
        float v1 = s[rf][1][r] * kC1 + (c1 ? (kC2 - kShift) : -kShift);
        float p0 = __builtin_exp2f(v0);
        float p1 = k1ok ? __builtin_exp2f(v1) : 0.f;
        lp[rf][r] += p0 + p1;
        // packed u32 store: f16 pos = llo*2+kf (key-permuted layout), chunk-swizzled
        union { f16 hh[2]; unsigned u; } pk;
        pk.hh[0] = (f16)p0; pk.hh[1] = (f16)p1;
        int row = rf * 16 + lhi * 4 + r;
        int dw = row * 16 + (((llo >> 2) ^ ((row >> 1) & 3)) << 2) + (llo & 3);
        reinterpret_cast<unsigned*>(P_lds[w])[dw] = pk.u;
      }
    }
    // ---- O += P V  (V stored with matching key permutation) ----
    f16x8 pa[2];
    #pragma unroll
    for (int rf = 0; rf < 2; rf++) {
      int row = rf * 16 + llo;
      pa[rf] = *reinterpret_cast<const f16x8*>(
          &P_lds[w][row * 32 + ((lhi ^ ((row >> 1) & 3)) << 3)]);
    }
    __builtin_amdgcn_s_setprio(1);
    #pragma unroll
    for (int d = 0; d < 4; d++) {
      f16x8 vv = *reinterpret_cast<const f16x8*>(
          &vb[(size_t)(d * 16 + llo) * kVPad + kbase + lhi * 8]);
      #pragma unroll
      for (int rf = 0; rf < 2; rf++)
        O[rf][d] = __builtin_amdgcn_mfma_f32_16x16x32_f16(pa[rf], vv, O[rf][d], 0, 0, 0);
    }
    __builtin_amdgcn_s_setprio(0);
  }
  // ---- row-sum reduce (once), normalize + store y[B,T,C] fp16 ----
  #pragma unroll
  for (int rf = 0; rf < 2; rf++)
    #pragma unroll
    for (int r = 0; r < 4; r++) {
      float l = lp[rf][r];
      l += __shfl_xor(l, 1, 64);
      l += __shfl_xor(l, 2, 64);
      l += __shfl_xor(l, 4, 64);
      l += __shfl_xor(l, 8, 64);
      int qi = qbase + rf * 16 + lhi * 4 + r;
      if (qi < kT) {
        float inv = 1.0f / l;
        size_t base = ((size_t)bb * kT + qi) * kC + h * kHD;
        #pragma unroll
        for (int d = 0; d < 4; d++)
          y[base + d * 16 + llo] = (f16)(O[rf][d][r] * inv);
      }
    }
}

}  // namespace

extern "C" void kernel_launch(void* const* d_in, const int* in_sizes, int n_in,
                              void* d_out, int out_size, void* d_ws, size_t ws_size,
                              hipStream_t stream) {
  const float* x  = (const float*)d_in[0];
  const float* Wa = (const float*)d_in[1];
  const float* ba = (const float*)d_in[2];
  const float* Wp = (const float*)d_in[3];
  const float* bp = (const float*)d_in[4];
  float* out = (float*)d_out;
  char* ws = (char*)d_ws;

  const size_t sz_xh = (size_t)kM * kC * 2;                 // 61.5 MB (x_h, later y_h)
  const size_t sz_wa = (size_t)3072 * 1024 * 2;             // 6.3 MB
  const size_t sz_wp = (size_t)1024 * 1024 * 2;             // 2.1 MB
  const size_t sz_q  = (size_t)kB * kH * kT * kHD * 2;      // 61.5 MB

  f16* xh  = (f16*)(ws);
  f16* WaT = (f16*)(ws + sz_xh);
  f16* WpT = (f16*)(ws + sz_xh + sz_wa);
  f16* qh  = (f16*)(ws + sz_xh + sz_wa + sz_wp);
  f16* kh2 = (f16*)(ws + sz_xh + sz_wa + sz_wp + sz_q);
  f16* vtt = (f16*)(ws + sz_xh + sz_wa + sz_wp + 2 * sz_q); // [bh][64][480], 62.9 MB
  f16* yh  = xh;                 // x_h dead after QKV GEMM
  f16* vtmp = (f16*)d_out;       // d_out (123 MB fp32) as scratch for v in [bh][t][d];
                                 // overwritten entirely by the proj GEMM at the end

  cast_kernel<<<2048, 256, 0, stream>>>(x, xh, kM * kC / 4);
  transpose_cast<<<dim3(32, 96), 256, 0, stream>>>(Wa, WaT, 1024, 3072);
  transpose_cast<<<dim3(32, 32), 256, 0, stream>>>(Wp, WpT, 1024, 1024);
  gemm_f16<0><<<24 * 235, 256, 0, stream>>>(xh, WaT, ba, qh, kh2, vtmp, nullptr, 24, 24 * 235);
  vtrans<<<kB * kH * 8, 256, 0, stream>>>(vtmp, vtt);
  attn_kernel<<<kB * kH * 4, 256, 0, stream>>>(qh, kh2, vtt, yh);
  gemm_f16<1><<<8 * 235, 256, 0, stream>>>(yh, WpT, bp, nullptr, nullptr, nullptr, out, 8, 8 * 235);
}

// Round 4
// 625.921 us; speedup vs baseline: 1.2254x; 1.0489x over previous
//
#include <hip/hip_runtime.h>

namespace {

constexpr int kT1   = 234;
constexpr int kT    = 469;          // sequence length
constexpr int kB    = 64;
constexpr int kC    = 1024;
constexpr int kH    = 16;
constexpr int kHD   = 64;
constexpr int kM    = kB * kT;      // 30016 rows
constexpr int kVPad = 480;          // padded T for v^T layout (15 tiles of 32)
// exp2-domain constants: p = exp(s*0.125 + mask - 4) = exp2(s*c1 + mask*c2 - 4*c2)
constexpr float kC1 = 0.125f * 1.44269504089f;
constexpr float kC2 = 1.44269504089f;
constexpr float kShift = 4.0f * 1.44269504089f;

typedef _Float16 f16;
typedef _Float16 f16x8 __attribute__((ext_vector_type(8)));
typedef float    f32x4 __attribute__((ext_vector_type(4)));

__device__ __forceinline__ void gload16(const void* g, void* l) {
  __builtin_amdgcn_global_load_lds(
      (const __attribute__((address_space(1))) unsigned int*)g,
      (__attribute__((address_space(3))) unsigned int*)l, 16, 0, 0);
}

// ---------------- cast fp32 -> fp16 (vectorized) ----------------
__global__ __launch_bounds__(256) void cast_kernel(const float* __restrict__ in,
                                                   f16* __restrict__ out, int n4) {
  int i = blockIdx.x * blockDim.x + threadIdx.x;
  int stride = gridDim.x * blockDim.x;
  for (int j = i; j < n4; j += stride) {
    float4 v = reinterpret_cast<const float4*>(in)[j];
    union { f16 h[4]; unsigned long long u; } pk;
    pk.h[0] = (f16)v.x; pk.h[1] = (f16)v.y; pk.h[2] = (f16)v.z; pk.h[3] = (f16)v.w;
    reinterpret_cast<unsigned long long*>(out)[j] = pk.u;
  }
}

// ---------------- transpose + cast: W[K0][N0] -> Wt[N0][K0] fp16 ----------------
__global__ __launch_bounds__(256) void transpose_cast(const float* __restrict__ W,
                                                      f16* __restrict__ Wt,
                                                      int K0, int N0) {
  __shared__ float tile[32][33];
  int kb = blockIdx.x * 32, nb = blockIdx.y * 32;
  int tx = threadIdx.x & 31, ty = threadIdx.x >> 5;
  #pragma unroll
  for (int r = ty; r < 32; r += 8) tile[r][tx] = W[(size_t)(kb + r) * N0 + nb + tx];
  __syncthreads();
  #pragma unroll
  for (int r = ty; r < 32; r += 8) Wt[(size_t)(nb + r) * K0 + kb + tx] = (f16)tile[tx][r];
}

// ---------------- v transpose: [bh][469][64] -> [bh][64][480] with per-32-tile
// key permutation pi(c) = (c&15)*2 + (c>>4)  (storage pos q holds key (q>>1)+(q&1)*16)
__global__ __launch_bounds__(256) void vtrans(const f16* __restrict__ in,
                                              f16* __restrict__ out) {
  __shared__ f16 tile[64][66];
  int bid = blockIdx.x;
  int bh = bid >> 3, tt = bid & 7;
  int t0 = tt * 64;
  int tx = threadIdx.x & 63, ty = threadIdx.x >> 6;
  const f16* src = in + (size_t)bh * kT * kHD;
  #pragma unroll
  for (int rr = ty; rr < 64; rr += 4) {
    int t = t0 + rr;
    tile[rr][tx] = (t < kT) ? src[(size_t)t * kHD + tx] : (f16)0.f;
  }
  __syncthreads();
  f16* dst = out + (size_t)bh * kHD * kVPad;
  int q = tx & 31, sub = tx >> 5;
  int tloc = sub * 32 + (q >> 1) + (q & 1) * 16;   // original local t for storage pos tx
  int tout = t0 + tx;
  if (tout < kVPad) {
    #pragma unroll
    for (int dd = ty; dd < 64; dd += 4)
      dst[(size_t)dd * kVPad + tout] = tile[tloc][dd];
  }
}

// ---------------- 256x256 GEMM, 2-phase/K-tile, counted vmcnt(8), 8 waves ----------------
// A[M][1024] * Bt[N][1024]^T (+bias).
// LDS: A blocks [buf][ks] 16KB each at SH[0..32768), B at SH[32768..65536).
// Each block = [256 rows][32 cols] f16, chunk-swizzled: phys16B = logical ^ ((row>>1)&3).
// EPI==0: QKV epilogue -> q,k,v as [B,H,T,64] fp16 (v into scratch)
// EPI==1: proj epilogue -> fp32 out[M][1024]
template <int EPI>
__global__ __launch_bounds__(512, 1) void gemm256(
    const f16* __restrict__ A, const f16* __restrict__ Bt,
    const float* __restrict__ bias,
    f16* __restrict__ qh, f16* __restrict__ kh, f16* __restrict__ vh,
    float* __restrict__ outp, int nbx, int nblocks) {
  __shared__ __align__(16) f16 SH[65536];   // 128 KiB
  const int K = 1024;
  // bijective XCD swizzle (nblocks % 8 == 0), n varies fastest within a chunk
  int flat = blockIdx.x;
  int swz = (flat & 7) * (nblocks >> 3) + (flat >> 3);
  int mt = swz / nbx;
  int m0 = mt * 256, n0 = (swz - mt * nbx) * 256;
  int tid = threadIdx.x;
  int wid = tid >> 6, lane = tid & 63;
  int wm = wid >> 2, wn = wid & 3;            // 2 x 4 wave grid; wave tile 128x64
  int lhi = lane >> 4, llo = lane & 15;

  // ---- staging geometry: thread handles 16B chunks ci0, ci1 of each 16KB region
  int ci0 = tid, ci1 = tid + 512;
  int r0 = ci0 >> 2, c0 = (ci0 & 3) ^ ((r0 >> 1) & 3);
  int r1 = ci1 >> 2, c1 = (ci1 & 3) ^ ((r1 >> 1) & 3);
  int gmA0 = m0 + r0; if (gmA0 >= kM) gmA0 = kM - 1;
  int gmA1 = m0 + r1; if (gmA1 >= kM) gmA1 = kM - 1;
  const f16* aS0 = A + (size_t)gmA0 * K + c0 * 8;
  const f16* aS1 = A + (size_t)gmA1 * K + c1 * 8;
  const f16* bS0 = Bt + (size_t)(n0 + r0) * K + c0 * 8;
  const f16* bS1 = Bt + (size_t)(n0 + r1) * K + c1 * 8;
  const int ld0 = ci0 * 8, ld1 = ci1 * 8;     // f16 offsets within region

  // stage one (tile, ks) region: 4 loads. reg = (buf*2+ks)*8192, kofs = t*64 + ks*32
  auto stage = [&](int reg, int kofs) {
    gload16(aS0 + kofs, &SH[reg + ld0]);
    gload16(aS1 + kofs, &SH[reg + ld1]);
    gload16(bS0 + kofs, &SH[32768 + reg + ld0]);
    gload16(bS1 + kofs, &SH[32768 + reg + ld1]);
  };

  // ---- per-thread ds_read offsets (f16 units), swizzle matches staging
  int aOff[8], bOff[4];
  #pragma unroll
  for (int mi = 0; mi < 8; mi++) {
    int row = wm * 128 + mi * 16 + llo;
    aOff[mi] = row * 32 + ((lhi ^ ((row >> 1) & 3)) << 3);
  }
  #pragma unroll
  for (int ni = 0; ni < 4; ni++) {
    int row = wn * 64 + ni * 16 + llo;
    bOff[ni] = row * 32 + ((lhi ^ ((row >> 1) & 3)) << 3);
  }

  const f32x4 zero4 = {0.f, 0.f, 0.f, 0.f};
  f32x4 acc[8][4];
  #pragma unroll
  for (int mi = 0; mi < 8; mi++)
    #pragma unroll
    for (int ni = 0; ni < 4; ni++) acc[mi][ni] = zero4;

  // ---- prologue: tiles 0 and 1 (16 loads)
  stage(0 * 8192, 0);
  stage(1 * 8192, 32);
  stage(2 * 8192, 64);
  stage(3 * 8192, 96);

  // ---- main loop: 16 K-tiles, 2 phases each
  for (int t = 0; t < 16; ++t) {
    int buf = t & 1;
    // ======== phase 0 (ks = 0) ========
    if (t < 15) asm volatile("s_waitcnt vmcnt(8)" ::: "memory");
    else        asm volatile("s_waitcnt vmcnt(4)" ::: "memory");
    __builtin_amdgcn_s_barrier();
    __builtin_amdgcn_sched_barrier(0);
    {
      int rb = (buf * 2 + 0) * 8192;
      f16x8 af[8], bf[4];
      #pragma unroll
      for (int mi = 0; mi < 8; mi++)
        af[mi] = *reinterpret_cast<const f16x8*>(&SH[rb + aOff[mi]]);
      #pragma unroll
      for (int ni = 0; ni < 4; ni++)
        bf[ni] = *reinterpret_cast<const f16x8*>(&SH[32768 + rb + bOff[ni]]);
      if (t >= 1 && t <= 14)                       // tile t+1, ks1 -> region freed last phase
        stage(((buf ^ 1) * 2 + 1) * 8192, (t + 1) * 64 + 32);
      asm volatile("s_waitcnt lgkmcnt(0)" ::: "memory");
      __builtin_amdgcn_sched_barrier(0);
      __builtin_amdgcn_s_setprio(1);
      #pragma unroll
      for (int mi = 0; mi < 8; mi++)
        #pragma unroll
        for (int ni = 0; ni < 4; ni++)
          acc[mi][ni] = __builtin_amdgcn_mfma_f32_16x16x32_f16(af[mi], bf[ni], acc[mi][ni], 0, 0, 0);
      __builtin_amdgcn_s_setprio(0);
    }
    // ======== phase 1 (ks = 1) ========
    if (t < 15) asm volatile("s_waitcnt vmcnt(8)" ::: "memory");
    else        asm volatile("s_waitcnt vmcnt(0)" ::: "memory");
    __builtin_amdgcn_s_barrier();
    __builtin_amdgcn_sched_barrier(0);
    {
      int rb = (buf * 2 + 1) * 8192;
      f16x8 af[8], bf[4];
      #pragma unroll
      for (int mi = 0; mi < 8; mi++)
        af[mi] = *reinterpret_cast<const f16x8*>(&SH[rb + aOff[mi]]);
      #pragma unroll
      for (int ni = 0; ni < 4; ni++)
        bf[ni] = *reinterpret_cast<const f16x8*>(&SH[32768 + rb + bOff[ni]]);
      if (t <= 13)                                 // tile t+2, ks0 -> region freed last phase
        stage((buf * 2 + 0) * 8192, (t + 2) * 64);
      asm volatile("s_waitcnt lgkmcnt(0)" ::: "memory");
      __builtin_amdgcn_sched_barrier(0);
      __builtin_amdgcn_s_setprio(1);
      #pragma unroll
      for (int mi = 0; mi < 8; mi++)
        #pragma unroll
        for (int ni = 0; ni < 4; ni++)
          acc[mi][ni] = __builtin_amdgcn_mfma_f32_16x16x32_f16(af[mi], bf[ni], acc[mi][ni], 0, 0, 0);
      __builtin_amdgcn_s_setprio(0);
    }
  }

  // ---- epilogue ----
  float bsv[4];
  #pragma unroll
  for (int ni = 0; ni < 4; ni++) bsv[ni] = bias[n0 + wn * 64 + ni * 16 + llo];

  if constexpr (EPI == 0) {
    const int which = n0 >> 10;            // 0:q 1:k 2:v (uniform per block, n0 mult of 256)
    f16* dst = (which == 0) ? qh : (which == 1) ? kh : vh;
    #pragma unroll
    for (int mi = 0; mi < 8; mi++) {
      #pragma unroll
      for (int rr = 0; rr < 4; rr++) {
        int row = m0 + wm * 128 + mi * 16 + lhi * 4 + rr;
        if (row < kM) {
          int bb = row / kT;
          int t  = row - bb * kT;
          #pragma unroll
          for (int ni = 0; ni < 4; ni++) {
            int n = n0 + wn * 64 + ni * 16 + llo;
            int h = (n >> 6) & 15, d = n & 63;
            dst[(((size_t)bb * kH + h) * kT + t) * kHD + d] = (f16)(acc[mi][ni][rr] + bsv[ni]);
          }
        }
      }
    }
  } else {
    #pragma unroll
    for (int mi = 0; mi < 8; mi++) {
      #pragma unroll
      for (int rr = 0; rr < 4; rr++) {
        int row = m0 + wm * 128 + mi * 16 + lhi * 4 + rr;
        if (row < kM) {
          #pragma unroll
          for (int ni = 0; ni < 4; ni++) {
            int n = n0 + wn * 64 + ni * 16 + llo;
            outp[(size_t)row * kC + n] = acc[mi][ni][rr] + bsv[ni];
          }
        }
      }
    }
  }
}

// ---------------- attention: fixed-shift softmax (no online max) ----------------
// grid: (B*H*4) blocks; block = 4 waves, wave owns 32 q-rows of a 128-row q-tile.
__global__ __launch_bounds__(256) void attn_kernel(
    const f16* __restrict__ qh, const f16* __restrict__ kh,
    const f16* __restrict__ vt, f16* __restrict__ y) {
  __shared__ __align__(16) f16 P_lds[4][32 * 32];   // per-wave 32x32, 64B rows
  int tid = threadIdx.x;
  int w = tid >> 6, lane = tid & 63;
  int lhi = lane >> 4, llo = lane & 15;
  // XCD swizzle: 4096 blocks -> chunks of 512 per XCD; same-head q-tiles stay on one L2
  int bid = (blockIdx.x & 7) * 512 + (blockIdx.x >> 3);
  int bh = bid >> 2, qt = bid & 3;
  int bb = bh >> 4, h = bh & 15;
  const f16* qb = qh + (size_t)bh * kT * kHD;
  const f16* kb = kh + (size_t)bh * kT * kHD;
  const f16* vb = vt + (size_t)bh * kHD * kVPad;
  int qbase = qt * 128 + w * 32;

  // Q fragments in registers: 2 row-frags x 2 k-steps
  f16x8 qf[2][2];
  bool qz[2][4], qle[2][4];
  #pragma unroll
  for (int rf = 0; rf < 2; rf++) {
    int qr = qbase + rf * 16 + llo;
    if (qr > kT - 1) qr = kT - 1;
    #pragma unroll
    for (int ks = 0; ks < 2; ks++)
      qf[rf][ks] = *reinterpret_cast<const f16x8*>(&qb[(size_t)qr * kHD + ks * 32 + lhi * 8]);
    #pragma unroll
    for (int r = 0; r < 4; r++) {
      int qi = qbase + rf * 16 + lhi * 4 + r;
      qz[rf][r]  = (qi == 0);
      qle[rf][r] = (qi <= kT1);
    }
  }

  const f32x4 zero4 = {0.f, 0.f, 0.f, 0.f};
  f32x4 O[2][4];
  float lp[2][4];
  #pragma unroll
  for (int rf = 0; rf < 2; rf++) {
    #pragma unroll
    for (int d = 0; d < 4; d++) O[rf][d] = zero4;
    #pragma unroll
    for (int r = 0; r < 4; r++) lp[rf][r] = 0.f;
  }

  for (int kt = 0; kt < 15; kt++) {
    int kbase = kt * 32;
    // ---- S = Q K^T ----
    f32x4 s[2][2];
    #pragma unroll
    for (int rf = 0; rf < 2; rf++)
      #pragma unroll
      for (int kf = 0; kf < 2; kf++) s[rf][kf] = zero4;
    __builtin_amdgcn_s_setprio(1);
    #pragma unroll
    for (int kf = 0; kf < 2; kf++) {
      int ky = kbase + kf * 16 + llo;
      if (ky > kT - 1) ky = kT - 1;
      #pragma unroll
      for (int ks = 0; ks < 2; ks++) {
        f16x8 kv = *reinterpret_cast<const f16x8*>(&kb[(size_t)ky * kHD + ks * 32 + lhi * 8]);
        #pragma unroll
        for (int rf = 0; rf < 2; rf++)
          s[rf][kf] = __builtin_amdgcn_mfma_f32_16x16x32_f16(qf[rf][ks], kv, s[rf][kf], 0, 0, 0);
      }
    }
    __builtin_amdgcn_s_setprio(0);
    // ---- P = exp2(s*c1 + mask*c2 - shift); accumulate per-lane row-sums ----
    int ki0 = kbase + llo;
    int ki1 = kbase + 16 + llo;
    bool kz0 = (ki0 == 0), kle0 = (ki0 <= kT1);
    bool kz1 = (ki1 == 0), kle1 = (ki1 <= kT1);
    bool k1ok = (ki1 < kT);                 // ki0 < 469 always (max 463)
    #pragma unroll
    for (int rf = 0; rf < 2; rf++) {
      #pragma unroll
      for (int r = 0; r < 4; r++) {
        bool c0 = qz[rf][r] | kz0 | (qle[rf][r] != kle0);
        bool c1 = qz[rf][r] | kz1 | (qle[rf][r] != kle1);
        float v0 = s[rf][0][r] * kC1 + (c0 ? (kC2 - kShift) : -kShift);
        float v1 = s[rf][1][r] * kC1 + (c1 ? (kC2 - kShift) : -kShift);
        float p0 = __builtin_exp2f(v0);
        float p1 = k1ok ? __builtin_exp2f(v1) : 0.f;
        lp[rf][r] += p0 + p1;
        // packed u32 store: f16 pos = llo*2+kf (key-permuted layout), chunk-swizzled
        union { f16 hh[2]; unsigned u; } pk;
        pk.hh[0] = (f16)p0; pk.hh[1] = (f16)p1;
        int row = rf * 16 + lhi * 4 + r;
        int dw = row * 16 + (((llo >> 2) ^ ((row >> 1) & 3)) << 2) + (llo & 3);
        reinterpret_cast<unsigned*>(P_lds[w])[dw] = pk.u;
      }
    }
    // ---- O += P V  (V stored with matching key permutation) ----
    f16x8 pa[2];
    #pragma unroll
    for (int rf = 0; rf < 2; rf++) {
      int row = rf * 16 + llo;
      pa[rf] = *reinterpret_cast<const f16x8*>(
          &P_lds[w][row * 32 + ((lhi ^ ((row >> 1) & 3)) << 3)]);
    }
    __builtin_amdgcn_s_setprio(1);
    #pragma unroll
    for (int d = 0; d < 4; d++) {
      f16x8 vv = *reinterpret_cast<const f16x8*>(
          &vb[(size_t)(d * 16 + llo) * kVPad + kbase + lhi * 8]);
      #pragma unroll
      for (int rf = 0; rf < 2; rf++)
        O[rf][d] = __builtin_amdgcn_mfma_f32_16x16x32_f16(pa[rf], vv, O[rf][d], 0, 0, 0);
    }
    __builtin_amdgcn_s_setprio(0);
  }
  // ---- row-sum reduce (once), normalize + store y[B,T,C] fp16 ----
  #pragma unroll
  for (int rf = 0; rf < 2; rf++)
    #pragma unroll
    for (int r = 0; r < 4; r++) {
      float l = lp[rf][r];
      l += __shfl_xor(l, 1, 64);
      l += __shfl_xor(l, 2, 64);
      l += __shfl_xor(l, 4, 64);
      l += __shfl_xor(l, 8, 64);
      int qi = qbase + rf * 16 + lhi * 4 + r;
      if (qi < kT) {
        float inv = 1.0f / l;
        size_t base = ((size_t)bb * kT + qi) * kC + h * kHD;
        #pragma unroll
        for (int d = 0; d < 4; d++)
          y[base + d * 16 + llo] = (f16)(O[rf][d][r] * inv);
      }
    }
}

}  // namespace

extern "C" void kernel_launch(void* const* d_in, const int* in_sizes, int n_in,
                              void* d_out, int out_size, void* d_ws, size_t ws_size,
                              hipStream_t stream) {
  const float* x  = (const float*)d_in[0];
  const float* Wa = (const float*)d_in[1];
  const float* ba = (const float*)d_in[2];
  const float* Wp = (const float*)d_in[3];
  const float* bp = (const float*)d_in[4];
  float* out = (float*)d_out;
  char* ws = (char*)d_ws;

  const size_t sz_xh = (size_t)kM * kC * 2;                 // 61.5 MB (x_h, later y_h)
  const size_t sz_wa = (size_t)3072 * 1024 * 2;             // 6.3 MB
  const size_t sz_wp = (size_t)1024 * 1024 * 2;             // 2.1 MB
  const size_t sz_q  = (size_t)kB * kH * kT * kHD * 2;      // 61.5 MB

  f16* xh  = (f16*)(ws);
  f16* WaT = (f16*)(ws + sz_xh);
  f16* WpT = (f16*)(ws + sz_xh + sz_wa);
  f16* qh  = (f16*)(ws + sz_xh + sz_wa + sz_wp);
  f16* kh2 = (f16*)(ws + sz_xh + sz_wa + sz_wp + sz_q);
  f16* vtt = (f16*)(ws + sz_xh + sz_wa + sz_wp + 2 * sz_q); // [bh][64][480], 62.9 MB
  f16* yh  = xh;                 // x_h dead after QKV GEMM
  f16* vtmp = (f16*)d_out;       // d_out (123 MB fp32) as scratch for v in [bh][t][d];
                                 // overwritten entirely by the proj GEMM at the end

  cast_kernel<<<2048, 256, 0, stream>>>(x, xh, kM * kC / 4);
  transpose_cast<<<dim3(32, 96), 256, 0, stream>>>(Wa, WaT, 1024, 3072);
  transpose_cast<<<dim3(32, 32), 256, 0, stream>>>(Wp, WpT, 1024, 1024);
  // QKV: M-tiles 118 (30208 >= 30016), N-tiles 12 -> 1416 blocks (= 8*177)
  gemm256<0><<<118 * 12, 512, 0, stream>>>(xh, WaT, ba, qh, kh2, vtmp, nullptr, 12, 118 * 12);
  vtrans<<<kB * kH * 8, 256, 0, stream>>>(vtmp, vtt);
  attn_kernel<<<kB * kH * 4, 256, 0, stream>>>(qh, kh2, vtt, yh);
  // proj: N-tiles 4 -> 472 blocks (= 8*59)
  gemm256<1><<<118 * 4, 512, 0, stream>>>(yh, WpT, bp, nullptr, nullptr, nullptr, out, 4, 118 * 4);
}